// Round 8
// baseline (1959.383 us; speedup 1.0000x reference)
//
#include <hip/hip_runtime.h>
#include <float.h>

// ---------------------------------------------------------------------------
// MPNN forward.  msg@w1 decomposed: per-node p=h@w1a, q=h@w1b (fused gemm_pq,
// f16 output), per-edge ea@w1c fp32 VALU; edge GEMM t1@w2 via f16 MFMA.
//
// R8: node_agg phase 1 is wave-autonomous (no staging barrier): per-wave
// metadata chain + per-wave LDS ea scratch + readlane-broadcast coalesced
// q loads, 8 edges in flight per wave.  Barriers/tile: 3 -> 2.
//
// ws budget: hard bound proven R2/R3: ws_size in [38,601,024, 38,617,408).
// Use: hagg f32 (12.8M) | pq f16 (12.8M) | ends (200K) | partials.
// perm/w2h/stats live in d_out (rebuilt each call; head GEMMs overwrite last).
// ---------------------------------------------------------------------------

typedef _Float16 half8 __attribute__((ext_vector_type(8)));
typedef _Float16 half4 __attribute__((ext_vector_type(4)));
typedef float floatx4 __attribute__((ext_vector_type(4)));

__device__ __forceinline__ unsigned enc(float f) {
    unsigned u = __float_as_uint(f);
    return (u & 0x80000000u) ? ~u : (u | 0x80000000u);
}
__device__ __forceinline__ float dec(unsigned u) {
    return (u & 0x80000000u) ? __uint_as_float(u & 0x7fffffffu)
                             : __uint_as_float(~u);
}

// ---------------------------------------------------------------------------
// Generic small GEMM: C[M][N] = op(A[M][64] @ W[64][N] + bias), K fixed = 64.
// ---------------------------------------------------------------------------
template<int N, int M_TILE, bool RELU, bool BIAS>
__global__ __launch_bounds__(256) void gemm_k64(
    const float* __restrict__ A, const float* __restrict__ W,
    const float* __restrict__ bias, float* __restrict__ C, int M)
{
    constexpr int K = 64;
    constexpr int TCOLS = N / 4;
    constexpr int TROWS = 256 / TCOLS;
    constexpr int RPT = M_TILE / TROWS;
    __shared__ __align__(16) float Ws[K * N];
    __shared__ __align__(16) float As[M_TILE * (K + 4)];

    const int t = threadIdx.x;
    const int m0 = blockIdx.x * M_TILE;

    for (int i = t; i < K * N; i += 256) Ws[i] = W[i];

    for (int rr = 0; rr < M_TILE; rr += 16) {
        int r = rr + (t >> 4);
        int c4 = (t & 15) * 4;
        int row = m0 + r;
        float4 v = make_float4(0.f, 0.f, 0.f, 0.f);
        if (row < M) v = *(const float4*)&A[(size_t)row * K + c4];
        *(float4*)&As[r * (K + 4) + c4] = v;
    }
    __syncthreads();

    const int tc = t % TCOLS;
    const int tr = t / TCOLS;
    float4 acc[RPT];
    float4 bv = make_float4(0.f, 0.f, 0.f, 0.f);
    if (BIAS) {
        bv.x = bias[tc * 4 + 0]; bv.y = bias[tc * 4 + 1];
        bv.z = bias[tc * 4 + 2]; bv.w = bias[tc * 4 + 3];
    }
#pragma unroll
    for (int i = 0; i < RPT; ++i) acc[i] = bv;

#pragma unroll 8
    for (int k = 0; k < K; ++k) {
        float4 w = *(const float4*)&Ws[k * N + tc * 4];
#pragma unroll
        for (int i = 0; i < RPT; ++i) {
            float a = As[(tr + i * TROWS) * (K + 4) + k];
            acc[i].x = fmaf(a, w.x, acc[i].x);
            acc[i].y = fmaf(a, w.y, acc[i].y);
            acc[i].z = fmaf(a, w.z, acc[i].z);
            acc[i].w = fmaf(a, w.w, acc[i].w);
        }
    }
#pragma unroll
    for (int i = 0; i < RPT; ++i) {
        int row = m0 + tr + i * TROWS;
        if (row < M) {
            float4 o = acc[i];
            if (RELU) {
                o.x = fmaxf(o.x, 0.f); o.y = fmaxf(o.y, 0.f);
                o.z = fmaxf(o.z, 0.f); o.w = fmaxf(o.w, 0.f);
            }
            *(float4*)&C[(size_t)row * N + tc * 4] = o;
        }
    }
}

// ---------------------------------------------------------------------------
// Fused p|q GEMM, f16 output: PQ[M][128] = (_Float16)(A[M][64] @ [w1a|w1b])
// ---------------------------------------------------------------------------
__global__ __launch_bounds__(256) void gemm_pq(
    const float* __restrict__ A, const float* __restrict__ W,
    _Float16* __restrict__ PQ, int M)
{
    __shared__ __align__(16) float Ws[64 * 128];
    __shared__ __align__(16) float As[64 * 68];

    const int t = threadIdx.x;
    const int m0 = blockIdx.x * 64;

    for (int i = t; i < 64 * 128; i += 256) {
        int k = i >> 7, n = i & 127;
        Ws[i] = W[(size_t)((n < 64 ? k : 64 + k)) * 64 + (n & 63)];
    }
    for (int rr = 0; rr < 64; rr += 16) {
        int r = rr + (t >> 4);
        int c4 = (t & 15) * 4;
        int row = m0 + r;
        float4 v = make_float4(0.f, 0.f, 0.f, 0.f);
        if (row < M) v = *(const float4*)&A[(size_t)row * 64 + c4];
        *(float4*)&As[r * 68 + c4] = v;
    }
    __syncthreads();

    const int tc = t & 31;
    const int tr = t >> 5;
    float4 acc[8];
#pragma unroll
    for (int i = 0; i < 8; ++i) acc[i] = make_float4(0.f, 0.f, 0.f, 0.f);

#pragma unroll 8
    for (int k = 0; k < 64; ++k) {
        float4 w = *(const float4*)&Ws[k * 128 + tc * 4];
#pragma unroll
        for (int i = 0; i < 8; ++i) {
            float a = As[(tr + i * 8) * 68 + k];
            acc[i].x = fmaf(a, w.x, acc[i].x);
            acc[i].y = fmaf(a, w.y, acc[i].y);
            acc[i].z = fmaf(a, w.z, acc[i].z);
            acc[i].w = fmaf(a, w.w, acc[i].w);
        }
    }
#pragma unroll
    for (int i = 0; i < 8; ++i) {
        int row = m0 + tr + i * 8;
        if (row < M) {
            half4 o = { (_Float16)acc[i].x, (_Float16)acc[i].y,
                        (_Float16)acc[i].z, (_Float16)acc[i].w };
            *(half4*)&PQ[(size_t)row * 128 + tc * 4] = o;
        }
    }
}

// ---------------------------------------------------------------------------
// CSR build: hist -> multi-block exclusive scan -> fill(perm)
// ---------------------------------------------------------------------------
__global__ __launch_bounds__(256) void hist_tgt(const int* __restrict__ tgt,
                                                int* __restrict__ cnt, int E)
{
    int e = blockIdx.x * 256 + threadIdx.x;
    if (e < E) atomicAdd(&cnt[tgt[e]], 1);
}

__global__ __launch_bounds__(256) void scan_partial(const int* __restrict__ cnt,
                                                    int* __restrict__ part, int M)
{
    __shared__ int s[256];
    int i = blockIdx.x * 256 + threadIdx.x;
    s[threadIdx.x] = (i < M) ? cnt[i] : 0;
    __syncthreads();
    for (int off = 128; off > 0; off >>= 1) {
        if (threadIdx.x < off) s[threadIdx.x] += s[threadIdx.x + off];
        __syncthreads();
    }
    if (threadIdx.x == 0) part[blockIdx.x] = s[0];
}

__global__ __launch_bounds__(256) void scan_part2(int* __restrict__ part, int nb)
{
    __shared__ int s[256];
    int t = threadIdx.x;
    int v = (t < nb) ? part[t] : 0;
    s[t] = v;
    __syncthreads();
    for (int off = 1; off < 256; off <<= 1) {
        int a = (t >= off) ? s[t - off] : 0;
        __syncthreads();
        s[t] += a;
        __syncthreads();
    }
    if (t < nb) part[t] = s[t] - v;   // exclusive
}

__global__ __launch_bounds__(256) void scan_add(int* __restrict__ cnt,
                                                const int* __restrict__ part, int M)
{
    __shared__ int s[256];
    int t = threadIdx.x;
    int i = blockIdx.x * 256 + t;
    int v = (i < M) ? cnt[i] : 0;
    s[t] = v;
    __syncthreads();
    for (int off = 1; off < 256; off <<= 1) {
        int a = (t >= off) ? s[t - off] : 0;
        __syncthreads();
        s[t] += a;
        __syncthreads();
    }
    if (i < M) cnt[i] = part[blockIdx.x] + s[t] - v;
}

__global__ __launch_bounds__(256) void fill_csr(const int* __restrict__ tgt,
    int* __restrict__ arr, int* __restrict__ perm, int E)
{
    int e = blockIdx.x * 256 + threadIdx.x;
    if (e < E) {
        int pos = atomicAdd(&arr[tgt[e]], 1);
        perm[pos] = e;
    }
}

// ---------------------------------------------------------------------------
// Pack w2 (both layers) into f16 MFMA B-fragment order.
// ---------------------------------------------------------------------------
__global__ __launch_bounds__(256) void pack_w2(const float* __restrict__ w2,
                                               _Float16* __restrict__ w2h)
{
    int id = blockIdx.x * 256 + threadIdx.x;
    if (id >= 1024) return;
    int l = id >> 9, rem = id & 511;
    int frag = rem >> 6, lane = rem & 63;
    int nt = frag >> 1, kc = frag & 1;
    const float* W = w2 + (size_t)l * 4096;
    _Float16* O = w2h + (size_t)l * 4096 + (frag * 64 + lane) * 8;
    int n = nt * 16 + (lane & 15);
    int k0 = kc * 32 + (lane >> 4) * 8;
#pragma unroll
    for (int j = 0; j < 8; ++j) O[j] = (_Float16)W[(k0 + j) * 64 + n];
}

// ---------------------------------------------------------------------------
// Fused per-node edge-MLP + segmented max + BN stats.
//   Phase 1 wave-autonomous: 8 edges in flight per wave, no staging barrier.
//   NPB=6 nodes/block (mean 96 edges, ET=128), LDS ~24.2 KB.
// ---------------------------------------------------------------------------
#define NPB 6
#define ET  128
#define TSH 72     // t1 LDS row stride in halfs (144 B -> 2-way b128, free)
#define EAS 20     // per-edge stride in wave ea scratch (floats)

__global__ __launch_bounds__(256, 5) void node_agg(
    const _Float16* __restrict__ pq, const float* __restrict__ ea,
    const int* __restrict__ srcG,
    const int* __restrict__ ends, const int* __restrict__ perm,
    const float* __restrict__ w1c, const float* __restrict__ b1,
    const _Float16* __restrict__ w2h, const float* __restrict__ b2,
    float* __restrict__ hout, float* __restrict__ stats, int M)
{
    __shared__ __align__(16) _Float16 t1h[ET * TSH];    // 18.4 KB
    __shared__ __align__(16) float eaw[4 * 8 * EAS];    //  2.56 KB (per-wave)
    __shared__ __align__(16) float ps[NPB * 64];        //  1.5 KB
    __shared__ __align__(16) unsigned rmu[NPB * 68];    //  1.6 KB
    __shared__ int endsL[NPB + 1];

    const int t = threadIdx.x;
    const int lane = t & 63;
    const int wid = t >> 6;
    const int n0 = blockIdx.x * NPB;
    const int c = lane;

    // w1c column c -> 16 VGPRs (coalesced, once per block)
    float w1r[16];
#pragma unroll
    for (int j = 0; j < 16; ++j) w1r[j] = w1c[j * 64 + c];

    if (t <= NPB) {
        int n = n0 + t - 1;
        endsL[t] = (t == 0) ? ((n0 == 0) ? 0 : ends[n0 - 1])
                            : ((n < M) ? ends[n] : ends[M - 1]);
    }
    for (int nn = wid; nn < NPB; nn += 4) {
        int node = n0 + nn;
        ps[nn * 64 + c] =
            ((node < M) ? (float)pq[(size_t)node * 128 + c] : 0.f) + b1[c];
    }
    for (int i = t; i < NPB * 68; i += 256) rmu[i] = 0u;   // 0 < enc(anything)

    // B fragments (w2), same for all waves
    half8 bfrag[4][2];
#pragma unroll
    for (int nt = 0; nt < 4; ++nt)
#pragma unroll
        for (int kc = 0; kc < 2; ++kc)
            bfrag[nt][kc] = *(const half8*)(w2h + ((nt * 2 + kc) * 64 + lane) * 8);

    __syncthreads();

    // endsL into per-lane registers (LDS broadcast reads)
    int endsR[NPB + 1];
#pragma unroll
    for (int k = 0; k <= NPB; ++k) endsR[k] = endsL[k];

    const int eBeg = endsR[0], eEnd = endsR[NPB];
    float* eawW = &eaw[wid * 8 * EAS];
    const int myE = lane & 7;          // edge slot this lane stages
    const int part = lane >> 3;        // which 1/8 of the edge's ea row

    for (int tile = eBeg; tile < eEnd; tile += ET) {
        const int cnt = min(ET, eEnd - tile);

        // ---- phase 1 (wave-autonomous, no barrier): 8 edges per iter ----
        for (int i0 = wid * 8; i0 < cnt; i0 += 32) {
            int gp  = tile + i0 + myE;
            int gpc = min(gp, eEnd - 1);
            int pe  = perm[gpc];               // lanes with same myE dedup
            int s   = srcG[pe];
            int L   = 0;
#pragma unroll
            for (int k = 1; k < NPB; ++k) L += (gpc >= endsR[k]) ? 1 : 0;

            // lane-parallel ea fetch: 2 floats of edge myE -> wave scratch
            float ea0 = ea[(size_t)pe * 16 + part];
            float ea1 = ea[(size_t)pe * 16 + 8 + part];
            eawW[myE * EAS + part] = ea0;
            eawW[myE * EAS + 8 + part] = ea1;

            // 8 coalesced q loads (readlane-uniform base) + ps
            float acc[8];
#pragma unroll
            for (int e = 0; e < 8; ++e) {
                int se = __shfl(s, e);
                int Le = __shfl(L, e);
                acc[e] = ps[Le * 64 + c]
                       + (float)pq[(size_t)se * 128 + 64 + c];
            }
            // intra-wave LDS dependency: compiler orders via lgkmcnt
#pragma unroll
            for (int j4 = 0; j4 < 4; ++j4) {
#pragma unroll
                for (int e = 0; e < 8; ++e) {
                    float4 ev = *(const float4*)&eawW[e * EAS + j4 * 4];
                    acc[e] = fmaf(ev.x, w1r[j4 * 4 + 0], acc[e]);
                    acc[e] = fmaf(ev.y, w1r[j4 * 4 + 1], acc[e]);
                    acc[e] = fmaf(ev.z, w1r[j4 * 4 + 2], acc[e]);
                    acc[e] = fmaf(ev.w, w1r[j4 * 4 + 3], acc[e]);
                }
            }
#pragma unroll
            for (int e = 0; e < 8; ++e) {
                int ie = i0 + e;
                if (ie < cnt)
                    t1h[ie * TSH + c] = (_Float16)fmaxf(acc[e], 0.f);
            }
        }
        __syncthreads();

        // ---- phase 2: m = t1 @ w2 via MFMA, segmented max into rmu ----
        {
            const int quad = lane >> 4;
            const int col = lane & 15;
            for (int mt = wid; mt * 16 < cnt; mt += 4) {
                const int e0 = mt * 16;
                floatx4 acc[4] = {{0.f,0.f,0.f,0.f},{0.f,0.f,0.f,0.f},
                                  {0.f,0.f,0.f,0.f},{0.f,0.f,0.f,0.f}};
#pragma unroll
                for (int kc = 0; kc < 2; ++kc) {
                    half8 a = *(const half8*)&t1h[(e0 + col) * TSH + kc * 32 + quad * 8];
#pragma unroll
                    for (int nt = 0; nt < 4; ++nt)
                        acc[nt] = __builtin_amdgcn_mfma_f32_16x16x32_f16(
                            a, bfrag[nt][kc], acc[nt], 0, 0, 0);
                }
                const int r0 = e0 + quad * 4;
#pragma unroll
                for (int nt = 0; nt < 4; ++nt) {
                    int curL = -1;
                    float best = 0.f;
#pragma unroll
                    for (int r = 0; r < 4; ++r) {
                        int ge = r0 + r;
                        if (ge < cnt) {
                            int gL = 0;
#pragma unroll
                            for (int k = 1; k < NPB; ++k)
                                gL += (tile + ge >= endsR[k]) ? 1 : 0;
                            float v = acc[nt][r];
                            if (gL != curL) {
                                if (curL >= 0)
                                    atomicMax(&rmu[curL * 68 + nt * 16 + col], enc(best));
                                curL = gL; best = v;
                            } else best = fmaxf(best, v);
                        }
                    }
                    if (curL >= 0)
                        atomicMax(&rmu[curL * 68 + nt * 16 + col], enc(best));
                }
            }
        }
        __syncthreads();
    }

    // ---- final store (+b2) + BN stats ----
    for (int idx = t; idx < NPB * 64; idx += 256) {
        int L = idx >> 6, cc = idx & 63;
        int node = n0 + L;
        float v = 0.f;
        if (node < M) {
            if (endsL[L + 1] > endsL[L]) v = dec(rmu[L * 68 + cc]) + b2[cc];
            hout[(size_t)node * 64 + cc] = v;
        }
        ((float*)rmu)[L * 68 + cc] = v;   // own slot: no race
    }
    __syncthreads();
    if (t < 64) {
        float s = 0.f, s2 = 0.f;
#pragma unroll
        for (int L = 0; L < NPB; ++L) {
            float v = ((float*)rmu)[L * 68 + t];
            s += v;
            s2 = fmaf(v, v, s2);
        }
        atomicAdd(&stats[t], s);
        atomicAdd(&stats[64 + t], s2);
    }
}

// ---------------------------------------------------------------------------
// BN normalize + relu, in place
// ---------------------------------------------------------------------------
__global__ __launch_bounds__(256) void bn_norm(float* __restrict__ h,
    const float* __restrict__ stats, const float* __restrict__ gamma,
    const float* __restrict__ beta, int M)
{
    int idx = blockIdx.x * 256 + threadIdx.x;
    if (idx >= M * 64) return;
    int c = idx & 63;
    float inv = 1.f / (float)M;
    float mu = stats[c] * inv;
    float var = fmaxf(stats[64 + c] * inv - mu * mu, 0.f);
    float v = h[idx];
    h[idx] = fmaxf(gamma[c] * (v - mu) * rsqrtf(var + 1e-5f) + beta[c], 0.f);
}

// ---------------------------------------------------------------------------
extern "C" void kernel_launch(void* const* d_in, const int* in_sizes, int n_in,
                              void* d_out, int out_size, void* d_ws, size_t ws_size,
                              hipStream_t stream)
{
    const float* x     = (const float*)d_in[0];
    const int*   eidx  = (const int*)  d_in[1];
    const float* ea    = (const float*)d_in[2];
    const float* w_in  = (const float*)d_in[3];
    const float* b_in  = (const float*)d_in[4];
    const float* w1    = (const float*)d_in[5];
    const float* b1    = (const float*)d_in[6];
    const float* w2    = (const float*)d_in[7];
    const float* b2    = (const float*)d_in[8];
    const float* gamma = (const float*)d_in[9];
    const float* beta  = (const float*)d_in[10];
    const float* w_m1  = (const float*)d_in[11];
    const float* b_m1  = (const float*)d_in[12];
    const float* w_m2  = (const float*)d_in[13];
    const float* b_m2  = (const float*)d_in[14];

    const int M = in_sizes[0] / 64;   // n_nodes
    const int E = in_sizes[1] / 2;    // n_edges
    const int* src = eidx;            // edge_index[0]
    const int* tgt = eidx + E;        // edge_index[1] (aggregation target)

    // ws: hagg f32[M*64] | pqh f16[M*128] | ends[M] | part[nb]  = 25.8 MB
    float* hagg     = (float*)d_ws;
    _Float16* pqh   = (_Float16*)(hagg + (size_t)M * 64);
    int*   ends     = (int*)(pqh + (size_t)M * 128);
    const int nb    = (M + 255) / 256;
    int*   part     = ends + M;
    // d_out scratch: perm[E] | w2h[2*4096 halfs] | stats[256 floats]
    int* perm = (int*)d_out;
    _Float16* w2h = (_Float16*)((char*)d_out + (size_t)E * 4);
    float* stats  = (float*)((char*)d_out + (size_t)E * 4 + 2 * 4096 * 2);

    dim3 blk(256);
    const int gm64  = (M + 63) / 64;
    const int gelem = (M * 64 + 255) / 256;
    const int gE    = (E + 255) / 256;

    // CSR build + weight pack
    hipMemsetAsync(ends, 0, (size_t)M * 4, stream);
    hipMemsetAsync(stats, 0, 256 * 4, stream);
    hist_tgt<<<gE, blk, 0, stream>>>(tgt, ends, E);
    scan_partial<<<nb, blk, 0, stream>>>(ends, part, M);
    scan_part2<<<1, blk, 0, stream>>>(part, nb);
    scan_add<<<nb, blk, 0, stream>>>(ends, part, M);
    fill_csr<<<gE, blk, 0, stream>>>(tgt, ends, perm, E);
    pack_w2<<<4, blk, 0, stream>>>(w2, w2h);

    // h0 = relu(x @ w_in + b_in)
    gemm_k64<64, 64, true, true><<<gm64, blk, 0, stream>>>(x, w_in, b_in, hagg, M);

    for (int l = 0; l < 2; ++l) {
        const float* w1l = w1 + (size_t)l * 144 * 64;
        gemm_pq<<<gm64, blk, 0, stream>>>(hagg, w1l, pqh, M);
        node_agg<<<(M + NPB - 1) / NPB, blk, 0, stream>>>(pqh, ea, src,
            ends, perm,
            w1l + 128 * 64, b1 + l * 64, w2h + (size_t)l * 4096, b2 + l * 64,
            hagg, stats + l * 128, M);
        bn_norm<<<gelem, blk, 0, stream>>>(hagg, stats + l * 128,
            gamma + l * 64, beta + l * 64, M);
    }

    // out = relu(h @ w_m1 + b_m1) @ w_m2 + b_m2
    gemm_k64<64, 64, true, true><<<gm64, blk, 0, stream>>>(hagg, w_m1, b_m1, (float*)pqh, M);
    gemm_k64<32, 64, false, true><<<gm64, blk, 0, stream>>>((float*)pqh, w_m2, b_m2, (float*)d_out, M);
}

// Round 9
// 813.081 us; speedup vs baseline: 2.4098x; 2.4098x over previous
//
#include <hip/hip_runtime.h>
#include <float.h>

// ---------------------------------------------------------------------------
// MPNN forward.  msg@w1 decomposed: per-node p=h@w1a, q=h@w1b (fused gemm_pq,
// f16 out, BN fused on A-load), per-edge ea@w1c fp32; edge GEMM t1@w2 f16 MFMA.
// R9: node_agg = R4 shape (NPB=8/ET=160, 3 blk/CU) + srcp materialized +
// 8-deep q-gather unroll @ launch_bounds(256,3) (R8 spill lesson: cap 170).
// Tail: BN fused into gemm_pq/head, fused 2-GEMM head, 13 dispatches.
//
// ws (proven bound 38,601,024 B): hagg 12.8M | pqh 12.8M | ends 200K |
//   srcp 3.2M | part | stats(256f)  = 29.0 MB.
// d_out scratch: perm 3.2M | w2h 16K (both dead before head writes d_out).
// ---------------------------------------------------------------------------

typedef _Float16 half8 __attribute__((ext_vector_type(8)));
typedef _Float16 half4 __attribute__((ext_vector_type(4)));
typedef float floatx4 __attribute__((ext_vector_type(4)));

#define BN_EPS 1e-5f

__device__ __forceinline__ unsigned enc(float f) {
    unsigned u = __float_as_uint(f);
    return (u & 0x80000000u) ? ~u : (u | 0x80000000u);
}
__device__ __forceinline__ float dec(unsigned u) {
    return (u & 0x80000000u) ? __uint_as_float(u & 0x7fffffffu)
                             : __uint_as_float(~u);
}

// ---------------------------------------------------------------------------
// h0 GEMM: C[M][64] = relu(A[M][64] @ W[64][64] + bias)
// ---------------------------------------------------------------------------
__global__ __launch_bounds__(256) void gemm_h0(
    const float* __restrict__ A, const float* __restrict__ W,
    const float* __restrict__ bias, float* __restrict__ C, int M)
{
    __shared__ __align__(16) float Ws[64 * 64];
    __shared__ __align__(16) float As[64 * 68];

    const int t = threadIdx.x;
    const int m0 = blockIdx.x * 64;

    for (int i = t; i < 64 * 64; i += 256) Ws[i] = W[i];
    for (int rr = 0; rr < 64; rr += 16) {
        int r = rr + (t >> 4);
        int c4 = (t & 15) * 4;
        int row = m0 + r;
        float4 v = make_float4(0.f, 0.f, 0.f, 0.f);
        if (row < M) v = *(const float4*)&A[(size_t)row * 64 + c4];
        *(float4*)&As[r * 68 + c4] = v;
    }
    __syncthreads();

    const int tc = t & 15, tr = t >> 4;
    float4 acc[4];
    float4 bv = *(const float4*)&bias[tc * 4];
#pragma unroll
    for (int i = 0; i < 4; ++i) acc[i] = bv;
#pragma unroll 8
    for (int k = 0; k < 64; ++k) {
        float4 w = *(const float4*)&Ws[k * 64 + tc * 4];
#pragma unroll
        for (int i = 0; i < 4; ++i) {
            float a = As[(tr + i * 16) * 68 + k];
            acc[i].x = fmaf(a, w.x, acc[i].x);
            acc[i].y = fmaf(a, w.y, acc[i].y);
            acc[i].z = fmaf(a, w.z, acc[i].z);
            acc[i].w = fmaf(a, w.w, acc[i].w);
        }
    }
#pragma unroll
    for (int i = 0; i < 4; ++i) {
        int row = m0 + tr + i * 16;
        if (row < M) {
            float4 o = acc[i];
            o.x = fmaxf(o.x, 0.f); o.y = fmaxf(o.y, 0.f);
            o.z = fmaxf(o.z, 0.f); o.w = fmaxf(o.w, 0.f);
            *(float4*)&C[(size_t)row * 64 + tc * 4] = o;
        }
    }
}

// ---------------------------------------------------------------------------
// Fused p|q GEMM, f16 out, optional BN+relu on A-load:
//   A' = BN ? relu(gamma*(A-mu)*rsqrt(var+eps)+beta) : A
//   PQ[M][128] = (f16)(A' @ [w1a|w1b])
// ---------------------------------------------------------------------------
template<bool BN>
__global__ __launch_bounds__(256) void gemm_pq(
    const float* __restrict__ A, const float* __restrict__ W,
    _Float16* __restrict__ PQ, const float* __restrict__ stats,
    const float* __restrict__ gamma, const float* __restrict__ beta, int M)
{
    __shared__ __align__(16) float Ws[64 * 128];
    __shared__ __align__(16) float As[64 * 68];

    const int t = threadIdx.x;
    const int m0 = blockIdx.x * 64;

    for (int i = t; i < 64 * 128; i += 256) {
        int k = i >> 7, n = i & 127;
        Ws[i] = W[(size_t)((n < 64 ? k : 64 + k)) * 64 + (n & 63)];
    }
    {
        int c4 = (t & 15) * 4;
        float sc[4], sh[4];
        if (BN) {
            float invM = 1.f / (float)M;
#pragma unroll
            for (int j = 0; j < 4; ++j) {
                int c = c4 + j;
                float mu = stats[c] * invM;
                float var = fmaxf(stats[64 + c] * invM - mu * mu, 0.f);
                float s = gamma[c] * rsqrtf(var + BN_EPS);
                sc[j] = s; sh[j] = beta[c] - mu * s;
            }
        }
        for (int rr = 0; rr < 64; rr += 16) {
            int r = rr + (t >> 4);
            int row = m0 + r;
            float4 v = make_float4(0.f, 0.f, 0.f, 0.f);
            if (row < M) v = *(const float4*)&A[(size_t)row * 64 + c4];
            if (BN) {
                v.x = fmaxf(fmaf(v.x, sc[0], sh[0]), 0.f);
                v.y = fmaxf(fmaf(v.y, sc[1], sh[1]), 0.f);
                v.z = fmaxf(fmaf(v.z, sc[2], sh[2]), 0.f);
                v.w = fmaxf(fmaf(v.w, sc[3], sh[3]), 0.f);
            }
            *(float4*)&As[r * 68 + c4] = v;
        }
    }
    __syncthreads();

    const int tc = t & 31, tr = t >> 5;
    float4 acc[8];
#pragma unroll
    for (int i = 0; i < 8; ++i) acc[i] = make_float4(0.f, 0.f, 0.f, 0.f);
#pragma unroll 8
    for (int k = 0; k < 64; ++k) {
        float4 w = *(const float4*)&Ws[k * 128 + tc * 4];
#pragma unroll
        for (int i = 0; i < 8; ++i) {
            float a = As[(tr + i * 8) * 68 + k];
            acc[i].x = fmaf(a, w.x, acc[i].x);
            acc[i].y = fmaf(a, w.y, acc[i].y);
            acc[i].z = fmaf(a, w.z, acc[i].z);
            acc[i].w = fmaf(a, w.w, acc[i].w);
        }
    }
#pragma unroll
    for (int i = 0; i < 8; ++i) {
        int row = m0 + tr + i * 8;
        if (row < M) {
            half4 o = { (_Float16)acc[i].x, (_Float16)acc[i].y,
                        (_Float16)acc[i].z, (_Float16)acc[i].w };
            *(half4*)&PQ[(size_t)row * 128 + tc * 4] = o;
        }
    }
}

// ---------------------------------------------------------------------------
// Fused head: out = relu(BN(h) @ w_m1 + b_m1) @ w_m2 + b_m2
// ---------------------------------------------------------------------------
__global__ __launch_bounds__(256) void head_fused(
    const float* __restrict__ hagg, const float* __restrict__ stats,
    const float* __restrict__ gamma, const float* __restrict__ beta,
    const float* __restrict__ w_m1, const float* __restrict__ b_m1,
    const float* __restrict__ w_m2, const float* __restrict__ b_m2,
    float* __restrict__ out, int M)
{
    __shared__ __align__(16) float Ws1[64 * 64];   // 16 KB
    __shared__ __align__(16) float Ws2[64 * 32];   //  8 KB
    __shared__ __align__(16) float As[64 * 68];    // 17.4 KB
    __shared__ __align__(16) float Ts[64 * 68];    // 17.4 KB

    const int t = threadIdx.x;
    const int m0 = blockIdx.x * 64;

    for (int i = t; i < 64 * 64; i += 256) Ws1[i] = w_m1[i];
    for (int i = t; i < 64 * 32; i += 256) Ws2[i] = w_m2[i];
    {
        int c4 = (t & 15) * 4;
        float sc[4], sh[4];
        float invM = 1.f / (float)M;
#pragma unroll
        for (int j = 0; j < 4; ++j) {
            int c = c4 + j;
            float mu = stats[c] * invM;
            float var = fmaxf(stats[64 + c] * invM - mu * mu, 0.f);
            float s = gamma[c] * rsqrtf(var + BN_EPS);
            sc[j] = s; sh[j] = beta[c] - mu * s;
        }
        for (int rr = 0; rr < 64; rr += 16) {
            int r = rr + (t >> 4);
            int row = m0 + r;
            float4 v = make_float4(0.f, 0.f, 0.f, 0.f);
            if (row < M) v = *(const float4*)&hagg[(size_t)row * 64 + c4];
            v.x = fmaxf(fmaf(v.x, sc[0], sh[0]), 0.f);
            v.y = fmaxf(fmaf(v.y, sc[1], sh[1]), 0.f);
            v.z = fmaxf(fmaf(v.z, sc[2], sh[2]), 0.f);
            v.w = fmaxf(fmaf(v.w, sc[3], sh[3]), 0.f);
            *(float4*)&As[r * 68 + c4] = v;
        }
    }
    __syncthreads();

    // GEMM1: Ts = relu(As @ Ws1 + b_m1)
    {
        const int tc = t & 15, tr = t >> 4;
        float4 acc[4];
        float4 bv = *(const float4*)&b_m1[tc * 4];
#pragma unroll
        for (int i = 0; i < 4; ++i) acc[i] = bv;
#pragma unroll 8
        for (int k = 0; k < 64; ++k) {
            float4 w = *(const float4*)&Ws1[k * 64 + tc * 4];
#pragma unroll
            for (int i = 0; i < 4; ++i) {
                float a = As[(tr + i * 16) * 68 + k];
                acc[i].x = fmaf(a, w.x, acc[i].x);
                acc[i].y = fmaf(a, w.y, acc[i].y);
                acc[i].z = fmaf(a, w.z, acc[i].z);
                acc[i].w = fmaf(a, w.w, acc[i].w);
            }
        }
#pragma unroll
        for (int i = 0; i < 4; ++i) {
            float4 o = acc[i];
            o.x = fmaxf(o.x, 0.f); o.y = fmaxf(o.y, 0.f);
            o.z = fmaxf(o.z, 0.f); o.w = fmaxf(o.w, 0.f);
            *(float4*)&Ts[(tr + i * 16) * 68 + tc * 4] = o;
        }
    }
    __syncthreads();

    // GEMM2: out = Ts @ Ws2 + b_m2
    {
        const int tc = t & 7, tr = t >> 3;     // 8 col-groups x 32 rows
        float4 acc[2];
        float4 bv = *(const float4*)&b_m2[tc * 4];
        acc[0] = bv; acc[1] = bv;
#pragma unroll 8
        for (int k = 0; k < 64; ++k) {
            float4 w = *(const float4*)&Ws2[k * 32 + tc * 4];
#pragma unroll
            for (int i = 0; i < 2; ++i) {
                float a = Ts[(tr + i * 32) * 68 + k];
                acc[i].x = fmaf(a, w.x, acc[i].x);
                acc[i].y = fmaf(a, w.y, acc[i].y);
                acc[i].z = fmaf(a, w.z, acc[i].z);
                acc[i].w = fmaf(a, w.w, acc[i].w);
            }
        }
#pragma unroll
        for (int i = 0; i < 2; ++i) {
            int row = m0 + tr + i * 32;
            if (row < M) *(float4*)&out[(size_t)row * 32 + tc * 4] = acc[i];
        }
    }
}

// ---------------------------------------------------------------------------
// CSR build: hist -> multi-block exclusive scan -> fill(perm + srcp)
// ---------------------------------------------------------------------------
__global__ __launch_bounds__(256) void hist_tgt(const int* __restrict__ tgt,
                                                int* __restrict__ cnt, int E)
{
    int e = blockIdx.x * 256 + threadIdx.x;
    if (e < E) atomicAdd(&cnt[tgt[e]], 1);
}

__global__ __launch_bounds__(256) void scan_partial(const int* __restrict__ cnt,
                                                    int* __restrict__ part, int M)
{
    __shared__ int s[256];
    int i = blockIdx.x * 256 + threadIdx.x;
    s[threadIdx.x] = (i < M) ? cnt[i] : 0;
    __syncthreads();
    for (int off = 128; off > 0; off >>= 1) {
        if (threadIdx.x < off) s[threadIdx.x] += s[threadIdx.x + off];
        __syncthreads();
    }
    if (threadIdx.x == 0) part[blockIdx.x] = s[0];
}

__global__ __launch_bounds__(256) void scan_part2(int* __restrict__ part, int nb)
{
    __shared__ int s[256];
    int t = threadIdx.x;
    int v = (t < nb) ? part[t] : 0;
    s[t] = v;
    __syncthreads();
    for (int off = 1; off < 256; off <<= 1) {
        int a = (t >= off) ? s[t - off] : 0;
        __syncthreads();
        s[t] += a;
        __syncthreads();
    }
    if (t < nb) part[t] = s[t] - v;   // exclusive
}

__global__ __launch_bounds__(256) void scan_add(int* __restrict__ cnt,
                                                const int* __restrict__ part, int M)
{
    __shared__ int s[256];
    int t = threadIdx.x;
    int i = blockIdx.x * 256 + t;
    int v = (i < M) ? cnt[i] : 0;
    s[t] = v;
    __syncthreads();
    for (int off = 1; off < 256; off <<= 1) {
        int a = (t >= off) ? s[t - off] : 0;
        __syncthreads();
        s[t] += a;
        __syncthreads();
    }
    if (i < M) cnt[i] = part[blockIdx.x] + s[t] - v;
}

__global__ __launch_bounds__(256) void fill_csr(const int* __restrict__ tgt,
    const int* __restrict__ src, int* __restrict__ arr,
    int* __restrict__ perm, int* __restrict__ srcp, int E)
{
    int e = blockIdx.x * 256 + threadIdx.x;
    if (e < E) {
        int pos = atomicAdd(&arr[tgt[e]], 1);
        perm[pos] = e;
        srcp[pos] = src[e];
    }
}

// ---------------------------------------------------------------------------
// Pack w2 into f16 MFMA B-frag order; also zero the BN stats accumulators.
// ---------------------------------------------------------------------------
__global__ __launch_bounds__(256) void pack_w2(const float* __restrict__ w2,
                                               _Float16* __restrict__ w2h,
                                               float* __restrict__ stats)
{
    int id = blockIdx.x * 256 + threadIdx.x;
    if (id < 256) stats[id] = 0.f;
    if (id >= 1024) return;
    int l = id >> 9, rem = id & 511;
    int frag = rem >> 6, lane = rem & 63;
    int nt = frag >> 1, kc = frag & 1;
    const float* W = w2 + (size_t)l * 4096;
    _Float16* O = w2h + (size_t)l * 4096 + (frag * 64 + lane) * 8;
    int n = nt * 16 + (lane & 15);
    int k0 = kc * 32 + (lane >> 4) * 8;
#pragma unroll
    for (int j = 0; j < 8; ++j) O[j] = (_Float16)W[(k0 + j) * 64 + n];
}

// ---------------------------------------------------------------------------
// Fused per-node edge-MLP + segmented max + BN stats.  MFMA phase 2.
//   R4 shape: NPB=8/ET=160, staged sidx/lnod/eas, 3 blocks/CU; phase-1 has
//   an 8-deep q-gather unroll (launch_bounds(256,3): VGPR cap 170, no spill).
// ---------------------------------------------------------------------------
#define NPB 8
#define ET  160
#define ETP (ET + 8)
#define TSH 72     // t1 stride in halfs (144 B -> 2-way b128, free)

__global__ __launch_bounds__(256, 3) void node_agg(
    const _Float16* __restrict__ pq, const float* __restrict__ ea,
    const int* __restrict__ ends, const int* __restrict__ perm,
    const int* __restrict__ srcp,
    const float* __restrict__ w1c, const float* __restrict__ b1,
    const _Float16* __restrict__ w2h, const float* __restrict__ b2,
    float* __restrict__ hout, float* __restrict__ stats, int M)
{
    __shared__ __align__(16) _Float16 t1h[ET * TSH];   // 23.0 KB
    __shared__ __align__(16) float eas[ETP * 16];      // 10.8 KB
    __shared__ __align__(16) float w1cs[16 * 64];      //  4.0 KB
    __shared__ __align__(16) float ps[NPB * 64];       //  2.0 KB
    __shared__ __align__(16) unsigned rmu[NPB * 68];   //  2.2 KB
    __shared__ __align__(16) int sidx[ETP];
    __shared__ int endsL[NPB + 1];
    __shared__ unsigned char lnodS[ETP];

    const int t = threadIdx.x;
    const int lane = t & 63;
    const int wid = t >> 6;
    const int n0 = blockIdx.x * NPB;
    const int c = lane;

    for (int i = t; i < 16 * 64; i += 256) w1cs[i] = w1c[i];
    if (t <= NPB) {
        int n = n0 + t - 1;
        endsL[t] = (t == 0) ? ((n0 == 0) ? 0 : ends[n0 - 1])
                            : ((n < M) ? ends[n] : ends[M - 1]);
    }
    for (int nn = wid; nn < NPB; nn += 4) {
        int node = n0 + nn;
        ps[nn * 64 + c] =
            ((node < M) ? (float)pq[(size_t)node * 128 + c] : 0.f) + b1[c];
    }
    for (int i = t; i < NPB * 68; i += 256) rmu[i] = 0u;   // 0 < enc(anything)

    half8 bfrag[4][2];
#pragma unroll
    for (int nt = 0; nt < 4; ++nt)
#pragma unroll
        for (int kc = 0; kc < 2; ++kc)
            bfrag[nt][kc] = *(const half8*)(w2h + ((nt * 2 + kc) * 64 + lane) * 8);

    __syncthreads();

    const int eBeg = endsL[0], eEnd = endsL[NPB];

    for (int tile = eBeg; tile < eEnd; tile += ET) {
        const int cnt = min(ET, eEnd - tile);

        // ---- stage metadata + edge_attr (one barrier) ----
        for (int i = t; i < ETP; i += 256) {
            if (i < cnt) {
                int gp = tile + i;
                sidx[i] = srcp[gp];           // direct: no perm hop
                int L = 0;
                while (gp >= endsL[L + 1]) ++L;
                lnodS[i] = (unsigned char)L;
            } else { sidx[i] = 0; lnodS[i] = 0; }
        }
        for (int i4 = t; i4 < ETP * 4; i4 += 256) {
            int ei = i4 >> 2, j4 = i4 & 3;
            float4 v = make_float4(0.f, 0.f, 0.f, 0.f);
            if (ei < cnt) {
                int pe = perm[tile + ei];
                v = *(const float4*)&ea[(size_t)pe * 16 + j4 * 4];
            }
            *(float4*)&eas[ei * 16 + j4 * 4] = v;
        }
        __syncthreads();

        // ---- phase 1: t1 = relu(p[tgt]+b1 + q[src] + ea@w1c) -> f16 LDS ----
        // 8-deep unroll: 8 independent q-gathers in flight per wave.
        for (int i0 = wid * 8; i0 < cnt; i0 += 32) {
            float acc[8];
#pragma unroll
            for (int e = 0; e < 8; ++e) {
                int ie = i0 + e;                       // < ETP (padded)
                acc[e] = ps[lnodS[ie] * 64 + c]
                       + (float)pq[(size_t)sidx[ie] * 128 + 64 + c];
            }
#pragma unroll
            for (int j4 = 0; j4 < 4; ++j4) {
                float w0 = w1cs[(j4 * 4 + 0) * 64 + c];
                float w1 = w1cs[(j4 * 4 + 1) * 64 + c];
                float w2v = w1cs[(j4 * 4 + 2) * 64 + c];
                float w3 = w1cs[(j4 * 4 + 3) * 64 + c];
#pragma unroll
                for (int e = 0; e < 8; ++e) {
                    float4 ev = *(const float4*)&eas[(i0 + e) * 16 + j4 * 4];
                    acc[e] = fmaf(ev.x, w0, acc[e]);
                    acc[e] = fmaf(ev.y, w1, acc[e]);
                    acc[e] = fmaf(ev.z, w2v, acc[e]);
                    acc[e] = fmaf(ev.w, w3, acc[e]);
                }
            }
#pragma unroll
            for (int e = 0; e < 8; ++e) {
                int ie = i0 + e;
                if (ie < cnt)
                    t1h[ie * TSH + c] = (_Float16)fmaxf(acc[e], 0.f);
            }
        }
        __syncthreads();

        // ---- phase 2: m = t1 @ w2 via MFMA, segmented max into rmu ----
        {
            const int quad = lane >> 4;
            const int col = lane & 15;
            for (int mt = wid; mt * 16 < cnt; mt += 4) {
                const int e0 = mt * 16;
                floatx4 acc[4] = {{0.f,0.f,0.f,0.f},{0.f,0.f,0.f,0.f},
                                  {0.f,0.f,0.f,0.f},{0.f,0.f,0.f,0.f}};
#pragma unroll
                for (int kc = 0; kc < 2; ++kc) {
                    half8 a = *(const half8*)&t1h[(e0 + col) * TSH + kc * 32 + quad * 8];
#pragma unroll
                    for (int nt = 0; nt < 4; ++nt)
                        acc[nt] = __builtin_amdgcn_mfma_f32_16x16x32_f16(
                            a, bfrag[nt][kc], acc[nt], 0, 0, 0);
                }
                const int r0 = e0 + quad * 4;
#pragma unroll
                for (int nt = 0; nt < 4; ++nt) {
                    int curL = -1;
                    float best = 0.f;
#pragma unroll
                    for (int r = 0; r < 4; ++r) {
                        int ge = r0 + r;
                        if (ge < cnt) {
                            int L = lnodS[ge];
                            float v = acc[nt][r];
                            if (L != curL) {
                                if (curL >= 0)
                                    atomicMax(&rmu[curL * 68 + nt * 16 + col], enc(best));
                                curL = L; best = v;
                            } else best = fmaxf(best, v);
                        }
                    }
                    if (curL >= 0)
                        atomicMax(&rmu[curL * 68 + nt * 16 + col], enc(best));
                }
            }
        }
        __syncthreads();
    }

    // ---- final store (+b2, raw agg; BN deferred to consumer) + BN stats ----
    for (int idx = t; idx < NPB * 64; idx += 256) {
        int L = idx >> 6, cc = idx & 63;
        int node = n0 + L;
        float v = 0.f;
        if (node < M) {
            if (endsL[L + 1] > endsL[L]) v = dec(rmu[L * 68 + cc]) + b2[cc];
            hout[(size_t)node * 64 + cc] = v;
        }
        ((float*)rmu)[L * 68 + cc] = v;   // own slot: no race
    }
    __syncthreads();
    if (t < 64) {
        float s = 0.f, s2 = 0.f;
#pragma unroll
        for (int L = 0; L < NPB; ++L) {
            float v = ((float*)rmu)[L * 68 + t];
            s += v;
            s2 = fmaf(v, v, s2);
        }
        atomicAdd(&stats[t], s);
        atomicAdd(&stats[64 + t], s2);
    }
}

// ---------------------------------------------------------------------------
extern "C" void kernel_launch(void* const* d_in, const int* in_sizes, int n_in,
                              void* d_out, int out_size, void* d_ws, size_t ws_size,
                              hipStream_t stream)
{
    const float* x     = (const float*)d_in[0];
    const int*   eidx  = (const int*)  d_in[1];
    const float* ea    = (const float*)d_in[2];
    const float* w_in  = (const float*)d_in[3];
    const float* b_in  = (const float*)d_in[4];
    const float* w1    = (const float*)d_in[5];
    const float* b1    = (const float*)d_in[6];
    const float* w2    = (const float*)d_in[7];
    const float* b2    = (const float*)d_in[8];
    const float* gamma = (const float*)d_in[9];
    const float* beta  = (const float*)d_in[10];
    const float* w_m1  = (const float*)d_in[11];
    const float* b_m1  = (const float*)d_in[12];
    const float* w_m2  = (const float*)d_in[13];
    const float* b_m2  = (const float*)d_in[14];

    const int M = in_sizes[0] / 64;   // n_nodes
    const int E = in_sizes[1] / 2;    // n_edges
    const int* src = eidx;            // edge_index[0]
    const int* tgt = eidx + E;        // edge_index[1] (aggregation target)

    // ws: hagg f32 | pqh f16 | ends | srcp | part | stats = 29.0 MB
    float* hagg   = (float*)d_ws;
    _Float16* pqh = (_Float16*)(hagg + (size_t)M * 64);
    int* ends     = (int*)(pqh + (size_t)M * 128);
    int* srcp     = ends + M;
    const int nb  = (M + 255) / 256;
    int* part     = srcp + E;
    float* stats  = (float*)(part + nb);
    // d_out scratch: perm[E] | w2h — dead before head writes d_out
    int* perm = (int*)d_out;
    _Float16* w2h = (_Float16*)((char*)d_out + (size_t)E * 4);

    dim3 blk(256);
    const int gm64 = (M + 63) / 64;
    const int gE   = (E + 255) / 256;

    // CSR build + weight pack (+stats zero)
    hipMemsetAsync(ends, 0, (size_t)M * 4, stream);
    hist_tgt<<<gE, blk, 0, stream>>>(tgt, ends, E);
    scan_partial<<<nb, blk, 0, stream>>>(ends, part, M);
    scan_part2<<<1, blk, 0, stream>>>(part, nb);
    scan_add<<<nb, blk, 0, stream>>>(ends, part, M);
    fill_csr<<<gE, blk, 0, stream>>>(tgt, src, ends, perm, srcp, E);
    pack_w2<<<4, blk, 0, stream>>>(w2, w2h, stats);

    // h0 = relu(x @ w_in + b_in)
    gemm_h0<<<gm64, blk, 0, stream>>>(x, w_in, b_in, hagg, M);

    for (int l = 0; l < 2; ++l) {
        const float* w1l = w1 + (size_t)l * 144 * 64;
        if (l == 0)
            gemm_pq<false><<<gm64, blk, 0, stream>>>(hagg, w1l, pqh,
                nullptr, nullptr, nullptr, M);
        else
            gemm_pq<true><<<gm64, blk, 0, stream>>>(hagg, w1l, pqh,
                stats, gamma, beta, M);
        node_agg<<<(M + NPB - 1) / NPB, blk, 0, stream>>>(pqh, ea,
            ends, perm, srcp,
            w1l + 128 * 64, b1 + l * 64, w2h + (size_t)l * 4096, b2 + l * 64,
            hagg, stats + l * 128, M);
    }

    // out = relu(BN1(h) @ w_m1 + b_m1) @ w_m2 + b_m2
    head_fused<<<gm64, blk, 0, stream>>>(hagg, stats + 128, gamma + 64, beta + 64,
        w_m1, b_m1, w_m2, b_m2, (float*)d_out, M);
}

// Round 10
// 774.993 us; speedup vs baseline: 2.5283x; 1.0491x over previous
//
#include <hip/hip_runtime.h>
#include <float.h>

// ---------------------------------------------------------------------------
// MPNN forward.  msg@w1 decomposed: per-node p=h@w1a, q=h@w1b (fused gemm_pq,
// f16 out, BN fused on A-load), per-edge ea@w1c fp32; edge GEMM t1@w2 f16 MFMA.
// R10: node_agg q-gather restructured as burst staging: 8 lanes x float4 per
// edge -> 8 independent line requests per wave instruction (vs 1 in R4-R9's
// per-edge loop).  q rows staged into the t1 LDS buffer; phase 1 computes
// in place.  Phase 1 is the simple loop (R8/R9 lesson: deep unrolls spill).
//
// ws (proven bound 38,601,024 B): hagg 12.8M | pqh 12.8M | ends 200K |
//   srcp 3.2M | part | stats(256f)  = 29.0 MB.
// d_out scratch: perm 3.2M | w2h 16K (both dead before head writes d_out).
// ---------------------------------------------------------------------------

typedef _Float16 half8 __attribute__((ext_vector_type(8)));
typedef _Float16 half4 __attribute__((ext_vector_type(4)));
typedef float floatx4 __attribute__((ext_vector_type(4)));

#define BN_EPS 1e-5f

__device__ __forceinline__ unsigned enc(float f) {
    unsigned u = __float_as_uint(f);
    return (u & 0x80000000u) ? ~u : (u | 0x80000000u);
}
__device__ __forceinline__ float dec(unsigned u) {
    return (u & 0x80000000u) ? __uint_as_float(u & 0x7fffffffu)
                             : __uint_as_float(~u);
}

// ---------------------------------------------------------------------------
// h0 GEMM: C[M][64] = relu(A[M][64] @ W[64][64] + bias)
// ---------------------------------------------------------------------------
__global__ __launch_bounds__(256) void gemm_h0(
    const float* __restrict__ A, const float* __restrict__ W,
    const float* __restrict__ bias, float* __restrict__ C, int M)
{
    __shared__ __align__(16) float Ws[64 * 64];
    __shared__ __align__(16) float As[64 * 68];

    const int t = threadIdx.x;
    const int m0 = blockIdx.x * 64;

    for (int i = t; i < 64 * 64; i += 256) Ws[i] = W[i];
    for (int rr = 0; rr < 64; rr += 16) {
        int r = rr + (t >> 4);
        int c4 = (t & 15) * 4;
        int row = m0 + r;
        float4 v = make_float4(0.f, 0.f, 0.f, 0.f);
        if (row < M) v = *(const float4*)&A[(size_t)row * 64 + c4];
        *(float4*)&As[r * 68 + c4] = v;
    }
    __syncthreads();

    const int tc = t & 15, tr = t >> 4;
    float4 acc[4];
    float4 bv = *(const float4*)&bias[tc * 4];
#pragma unroll
    for (int i = 0; i < 4; ++i) acc[i] = bv;
#pragma unroll 8
    for (int k = 0; k < 64; ++k) {
        float4 w = *(const float4*)&Ws[k * 64 + tc * 4];
#pragma unroll
        for (int i = 0; i < 4; ++i) {
            float a = As[(tr + i * 16) * 68 + k];
            acc[i].x = fmaf(a, w.x, acc[i].x);
            acc[i].y = fmaf(a, w.y, acc[i].y);
            acc[i].z = fmaf(a, w.z, acc[i].z);
            acc[i].w = fmaf(a, w.w, acc[i].w);
        }
    }
#pragma unroll
    for (int i = 0; i < 4; ++i) {
        int row = m0 + tr + i * 16;
        if (row < M) {
            float4 o = acc[i];
            o.x = fmaxf(o.x, 0.f); o.y = fmaxf(o.y, 0.f);
            o.z = fmaxf(o.z, 0.f); o.w = fmaxf(o.w, 0.f);
            *(float4*)&C[(size_t)row * 64 + tc * 4] = o;
        }
    }
}

// ---------------------------------------------------------------------------
// Fused p|q GEMM, f16 out, optional BN+relu on A-load.
// ---------------------------------------------------------------------------
template<bool BN>
__global__ __launch_bounds__(256) void gemm_pq(
    const float* __restrict__ A, const float* __restrict__ W,
    _Float16* __restrict__ PQ, const float* __restrict__ stats,
    const float* __restrict__ gamma, const float* __restrict__ beta, int M)
{
    __shared__ __align__(16) float Ws[64 * 128];
    __shared__ __align__(16) float As[64 * 68];

    const int t = threadIdx.x;
    const int m0 = blockIdx.x * 64;

    for (int i = t; i < 64 * 128; i += 256) {
        int k = i >> 7, n = i & 127;
        Ws[i] = W[(size_t)((n < 64 ? k : 64 + k)) * 64 + (n & 63)];
    }
    {
        int c4 = (t & 15) * 4;
        float sc[4], sh[4];
        if (BN) {
            float invM = 1.f / (float)M;
#pragma unroll
            for (int j = 0; j < 4; ++j) {
                int c = c4 + j;
                float mu = stats[c] * invM;
                float var = fmaxf(stats[64 + c] * invM - mu * mu, 0.f);
                float s = gamma[c] * rsqrtf(var + BN_EPS);
                sc[j] = s; sh[j] = beta[c] - mu * s;
            }
        }
        for (int rr = 0; rr < 64; rr += 16) {
            int r = rr + (t >> 4);
            int row = m0 + r;
            float4 v = make_float4(0.f, 0.f, 0.f, 0.f);
            if (row < M) v = *(const float4*)&A[(size_t)row * 64 + c4];
            if (BN) {
                v.x = fmaxf(fmaf(v.x, sc[0], sh[0]), 0.f);
                v.y = fmaxf(fmaf(v.y, sc[1], sh[1]), 0.f);
                v.z = fmaxf(fmaf(v.z, sc[2], sh[2]), 0.f);
                v.w = fmaxf(fmaf(v.w, sc[3], sh[3]), 0.f);
            }
            *(float4*)&As[r * 68 + c4] = v;
        }
    }
    __syncthreads();

    const int tc = t & 31, tr = t >> 5;
    float4 acc[8];
#pragma unroll
    for (int i = 0; i < 8; ++i) acc[i] = make_float4(0.f, 0.f, 0.f, 0.f);
#pragma unroll 8
    for (int k = 0; k < 64; ++k) {
        float4 w = *(const float4*)&Ws[k * 128 + tc * 4];
#pragma unroll
        for (int i = 0; i < 8; ++i) {
            float a = As[(tr + i * 8) * 68 + k];
            acc[i].x = fmaf(a, w.x, acc[i].x);
            acc[i].y = fmaf(a, w.y, acc[i].y);
            acc[i].z = fmaf(a, w.z, acc[i].z);
            acc[i].w = fmaf(a, w.w, acc[i].w);
        }
    }
#pragma unroll
    for (int i = 0; i < 8; ++i) {
        int row = m0 + tr + i * 8;
        if (row < M) {
            half4 o = { (_Float16)acc[i].x, (_Float16)acc[i].y,
                        (_Float16)acc[i].z, (_Float16)acc[i].w };
            *(half4*)&PQ[(size_t)row * 128 + tc * 4] = o;
        }
    }
}

// ---------------------------------------------------------------------------
// Fused head: out = relu(BN(h) @ w_m1 + b_m1) @ w_m2 + b_m2
// ---------------------------------------------------------------------------
__global__ __launch_bounds__(256) void head_fused(
    const float* __restrict__ hagg, const float* __restrict__ stats,
    const float* __restrict__ gamma, const float* __restrict__ beta,
    const float* __restrict__ w_m1, const float* __restrict__ b_m1,
    const float* __restrict__ w_m2, const float* __restrict__ b_m2,
    float* __restrict__ out, int M)
{
    __shared__ __align__(16) float Ws1[64 * 64];
    __shared__ __align__(16) float Ws2[64 * 32];
    __shared__ __align__(16) float As[64 * 68];
    __shared__ __align__(16) float Ts[64 * 68];

    const int t = threadIdx.x;
    const int m0 = blockIdx.x * 64;

    for (int i = t; i < 64 * 64; i += 256) Ws1[i] = w_m1[i];
    for (int i = t; i < 64 * 32; i += 256) Ws2[i] = w_m2[i];
    {
        int c4 = (t & 15) * 4;
        float sc[4], sh[4];
        float invM = 1.f / (float)M;
#pragma unroll
        for (int j = 0; j < 4; ++j) {
            int c = c4 + j;
            float mu = stats[c] * invM;
            float var = fmaxf(stats[64 + c] * invM - mu * mu, 0.f);
            float s = gamma[c] * rsqrtf(var + BN_EPS);
            sc[j] = s; sh[j] = beta[c] - mu * s;
        }
        for (int rr = 0; rr < 64; rr += 16) {
            int r = rr + (t >> 4);
            int row = m0 + r;
            float4 v = make_float4(0.f, 0.f, 0.f, 0.f);
            if (row < M) v = *(const float4*)&hagg[(size_t)row * 64 + c4];
            v.x = fmaxf(fmaf(v.x, sc[0], sh[0]), 0.f);
            v.y = fmaxf(fmaf(v.y, sc[1], sh[1]), 0.f);
            v.z = fmaxf(fmaf(v.z, sc[2], sh[2]), 0.f);
            v.w = fmaxf(fmaf(v.w, sc[3], sh[3]), 0.f);
            *(float4*)&As[r * 68 + c4] = v;
        }
    }
    __syncthreads();

    {
        const int tc = t & 15, tr = t >> 4;
        float4 acc[4];
        float4 bv = *(const float4*)&b_m1[tc * 4];
#pragma unroll
        for (int i = 0; i < 4; ++i) acc[i] = bv;
#pragma unroll 8
        for (int k = 0; k < 64; ++k) {
            float4 w = *(const float4*)&Ws1[k * 64 + tc * 4];
#pragma unroll
            for (int i = 0; i < 4; ++i) {
                float a = As[(tr + i * 16) * 68 + k];
                acc[i].x = fmaf(a, w.x, acc[i].x);
                acc[i].y = fmaf(a, w.y, acc[i].y);
                acc[i].z = fmaf(a, w.z, acc[i].z);
                acc[i].w = fmaf(a, w.w, acc[i].w);
            }
        }
#pragma unroll
        for (int i = 0; i < 4; ++i) {
            float4 o = acc[i];
            o.x = fmaxf(o.x, 0.f); o.y = fmaxf(o.y, 0.f);
            o.z = fmaxf(o.z, 0.f); o.w = fmaxf(o.w, 0.f);
            *(float4*)&Ts[(tr + i * 16) * 68 + tc * 4] = o;
        }
    }
    __syncthreads();

    {
        const int tc = t & 7, tr = t >> 3;
        float4 acc[2];
        float4 bv = *(const float4*)&b_m2[tc * 4];
        acc[0] = bv; acc[1] = bv;
#pragma unroll 8
        for (int k = 0; k < 64; ++k) {
            float4 w = *(const float4*)&Ws2[k * 32 + tc * 4];
#pragma unroll
            for (int i = 0; i < 2; ++i) {
                float a = Ts[(tr + i * 32) * 68 + k];
                acc[i].x = fmaf(a, w.x, acc[i].x);
                acc[i].y = fmaf(a, w.y, acc[i].y);
                acc[i].z = fmaf(a, w.z, acc[i].z);
                acc[i].w = fmaf(a, w.w, acc[i].w);
            }
        }
#pragma unroll
        for (int i = 0; i < 2; ++i) {
            int row = m0 + tr + i * 32;
            if (row < M) *(float4*)&out[(size_t)row * 32 + tc * 4] = acc[i];
        }
    }
}

// ---------------------------------------------------------------------------
// CSR build: hist -> multi-block exclusive scan -> fill(perm + srcp)
// ---------------------------------------------------------------------------
__global__ __launch_bounds__(256) void hist_tgt(const int* __restrict__ tgt,
                                                int* __restrict__ cnt, int E)
{
    int e = blockIdx.x * 256 + threadIdx.x;
    if (e < E) atomicAdd(&cnt[tgt[e]], 1);
}

__global__ __launch_bounds__(256) void scan_partial(const int* __restrict__ cnt,
                                                    int* __restrict__ part, int M)
{
    __shared__ int s[256];
    int i = blockIdx.x * 256 + threadIdx.x;
    s[threadIdx.x] = (i < M) ? cnt[i] : 0;
    __syncthreads();
    for (int off = 128; off > 0; off >>= 1) {
        if (threadIdx.x < off) s[threadIdx.x] += s[threadIdx.x + off];
        __syncthreads();
    }
    if (threadIdx.x == 0) part[blockIdx.x] = s[0];
}

__global__ __launch_bounds__(256) void scan_part2(int* __restrict__ part, int nb)
{
    __shared__ int s[256];
    int t = threadIdx.x;
    int v = (t < nb) ? part[t] : 0;
    s[t] = v;
    __syncthreads();
    for (int off = 1; off < 256; off <<= 1) {
        int a = (t >= off) ? s[t - off] : 0;
        __syncthreads();
        s[t] += a;
        __syncthreads();
    }
    if (t < nb) part[t] = s[t] - v;   // exclusive
}

__global__ __launch_bounds__(256) void scan_add(int* __restrict__ cnt,
                                                const int* __restrict__ part, int M)
{
    __shared__ int s[256];
    int t = threadIdx.x;
    int i = blockIdx.x * 256 + t;
    int v = (i < M) ? cnt[i] : 0;
    s[t] = v;
    __syncthreads();
    for (int off = 1; off < 256; off <<= 1) {
        int a = (t >= off) ? s[t - off] : 0;
        __syncthreads();
        s[t] += a;
        __syncthreads();
    }
    if (i < M) cnt[i] = part[blockIdx.x] + s[t] - v;
}

__global__ __launch_bounds__(256) void fill_csr(const int* __restrict__ tgt,
    const int* __restrict__ src, int* __restrict__ arr,
    int* __restrict__ perm, int* __restrict__ srcp, int E)
{
    int e = blockIdx.x * 256 + threadIdx.x;
    if (e < E) {
        int pos = atomicAdd(&arr[tgt[e]], 1);
        perm[pos] = e;
        srcp[pos] = src[e];
    }
}

// ---------------------------------------------------------------------------
// Pack w2 into f16 MFMA B-frag order; also zero the BN stats accumulators.
// ---------------------------------------------------------------------------
__global__ __launch_bounds__(256) void pack_w2(const float* __restrict__ w2,
                                               _Float16* __restrict__ w2h,
                                               float* __restrict__ stats)
{
    int id = blockIdx.x * 256 + threadIdx.x;
    if (id < 256) stats[id] = 0.f;
    if (id >= 1024) return;
    int l = id >> 9, rem = id & 511;
    int frag = rem >> 6, lane = rem & 63;
    int nt = frag >> 1, kc = frag & 1;
    const float* W = w2 + (size_t)l * 4096;
    _Float16* O = w2h + (size_t)l * 4096 + (frag * 64 + lane) * 8;
    int n = nt * 16 + (lane & 15);
    int k0 = kc * 32 + (lane >> 4) * 8;
#pragma unroll
    for (int j = 0; j < 8; ++j) O[j] = (_Float16)W[(k0 + j) * 64 + n];
}

// ---------------------------------------------------------------------------
// Fused per-node edge-MLP + segmented max + BN stats.
//   q-gather burst-staged: 8 lanes x float4 per edge row -> 8 line requests
//   per wave instruction, into the t1 LDS buffer; phase 1 computes in place.
// ---------------------------------------------------------------------------
#define NPB 8
#define ET  160
#define TSH 72     // t1/q stride in halfs (144 B -> 2-way b128, free)

__global__ __launch_bounds__(256, 3) void node_agg(
    const _Float16* __restrict__ pq, const float* __restrict__ ea,
    const int* __restrict__ ends, const int* __restrict__ perm,
    const int* __restrict__ srcp,
    const float* __restrict__ w1c, const float* __restrict__ b1,
    const _Float16* __restrict__ w2h, const float* __restrict__ b2,
    float* __restrict__ hout, float* __restrict__ stats, int M)
{
    __shared__ __align__(16) _Float16 t1h[ET * TSH];   // 23.0 KB (q, then t1)
    __shared__ __align__(16) float eas[ET * 16];       // 10.2 KB
    __shared__ __align__(16) float w1cs[16 * 64];      //  4.0 KB
    __shared__ __align__(16) float ps[NPB * 64];       //  2.0 KB
    __shared__ __align__(16) unsigned rmu[NPB * 68];   //  2.2 KB
    __shared__ __align__(16) int sidx[ET];
    __shared__ int endsL[NPB + 1];
    __shared__ unsigned char lnodS[ET];

    const int t = threadIdx.x;
    const int lane = t & 63;
    const int wid = t >> 6;
    const int n0 = blockIdx.x * NPB;
    const int c = lane;

    for (int i = t; i < 16 * 64; i += 256) w1cs[i] = w1c[i];
    if (t <= NPB) {
        int n = n0 + t - 1;
        endsL[t] = (t == 0) ? ((n0 == 0) ? 0 : ends[n0 - 1])
                            : ((n < M) ? ends[n] : ends[M - 1]);
    }
    for (int nn = wid; nn < NPB; nn += 4) {
        int node = n0 + nn;
        ps[nn * 64 + c] =
            ((node < M) ? (float)pq[(size_t)node * 128 + c] : 0.f) + b1[c];
    }
    for (int i = t; i < NPB * 68; i += 256) rmu[i] = 0u;   // 0 < enc(anything)

    half8 bfrag[4][2];
#pragma unroll
    for (int nt = 0; nt < 4; ++nt)
#pragma unroll
        for (int kc = 0; kc < 2; ++kc)
            bfrag[nt][kc] = *(const half8*)(w2h + ((nt * 2 + kc) * 64 + lane) * 8);

    __syncthreads();

    const int eBeg = endsL[0], eEnd = endsL[NPB];

    for (int tile = eBeg; tile < eEnd; tile += ET) {
        const int cnt = min(ET, eEnd - tile);

        // ---- A: stage metadata + edge_attr ----
        for (int i = t; i < ET; i += 256) {
            if (i < cnt) {
                int gp = tile + i;
                sidx[i] = srcp[gp];
                int L = 0;
                while (gp >= endsL[L + 1]) ++L;
                lnodS[i] = (unsigned char)L;
            } else { sidx[i] = 0; lnodS[i] = 0; }
        }
        for (int i4 = t; i4 < ET * 4; i4 += 256) {
            int ei = i4 >> 2, j4 = i4 & 3;
            float4 v = make_float4(0.f, 0.f, 0.f, 0.f);
            if (ei < cnt) {
                int pe = perm[tile + ei];
                v = *(const float4*)&ea[(size_t)pe * 16 + j4 * 4];
            }
            *(float4*)&eas[ei * 16 + j4 * 4] = v;
        }
        __syncthreads();

        // ---- B: burst-stage q rows into t1h (8 lanes x 16 B per edge) ----
        // each 256-thread round touches 32 distinct q rows -> 8 independent
        // line requests per wave instruction.
        for (int i8 = t; i8 < cnt * 8; i8 += 256) {
            int ei = i8 >> 3, sub = i8 & 7;
            half8 v = *(const half8*)&pq[(size_t)sidx[ei] * 128 + 64 + sub * 8];
            *(half8*)&t1h[ei * TSH + sub * 8] = v;
        }
        __syncthreads();

        // ---- C: t1 = relu(p[tgt]+b1 + q + ea@w1c), in place ----
        for (int i = wid; i < cnt; i += 4) {
            float acc = ps[lnodS[i] * 64 + c] + (float)t1h[i * TSH + c];
#pragma unroll
            for (int j4 = 0; j4 < 4; ++j4) {
                float4 ev = *(const float4*)&eas[i * 16 + j4 * 4];
                acc = fmaf(ev.x, w1cs[(j4 * 4 + 0) * 64 + c], acc);
                acc = fmaf(ev.y, w1cs[(j4 * 4 + 1) * 64 + c], acc);
                acc = fmaf(ev.z, w1cs[(j4 * 4 + 2) * 64 + c], acc);
                acc = fmaf(ev.w, w1cs[(j4 * 4 + 3) * 64 + c], acc);
            }
            t1h[i * TSH + c] = (_Float16)fmaxf(acc, 0.f);
        }
        __syncthreads();

        // ---- D: m = t1 @ w2 via MFMA, segmented max into rmu ----
        {
            const int quad = lane >> 4;
            const int col = lane & 15;
            for (int mt = wid; mt * 16 < cnt; mt += 4) {
                const int e0 = mt * 16;
                floatx4 acc[4] = {{0.f,0.f,0.f,0.f},{0.f,0.f,0.f,0.f},
                                  {0.f,0.f,0.f,0.f},{0.f,0.f,0.f,0.f}};
#pragma unroll
                for (int kc = 0; kc < 2; ++kc) {
                    half8 a = *(const half8*)&t1h[(e0 + col) * TSH + kc * 32 + quad * 8];
#pragma unroll
                    for (int nt = 0; nt < 4; ++nt)
                        acc[nt] = __builtin_amdgcn_mfma_f32_16x16x32_f16(
                            a, bfrag[nt][kc], acc[nt], 0, 0, 0);
                }
                const int r0 = e0 + quad * 4;
#pragma unroll
                for (int nt = 0; nt < 4; ++nt) {
                    int curL = -1;
                    float best = 0.f;
#pragma unroll
                    for (int r = 0; r < 4; ++r) {
                        int ge = r0 + r;
                        if (ge < cnt) {
                            int L = lnodS[ge];
                            float v = acc[nt][r];
                            if (L != curL) {
                                if (curL >= 0)
                                    atomicMax(&rmu[curL * 68 + nt * 16 + col], enc(best));
                                curL = L; best = v;
                            } else best = fmaxf(best, v);
                        }
                    }
                    if (curL >= 0)
                        atomicMax(&rmu[curL * 68 + nt * 16 + col], enc(best));
                }
            }
        }
        __syncthreads();
    }

    // ---- final store (+b2, raw agg; BN deferred to consumer) + BN stats ----
    for (int idx = t; idx < NPB * 64; idx += 256) {
        int L = idx >> 6, cc = idx & 63;
        int node = n0 + L;
        float v = 0.f;
        if (node < M) {
            if (endsL[L + 1] > endsL[L]) v = dec(rmu[L * 68 + cc]) + b2[cc];
            hout[(size_t)node * 64 + cc] = v;
        }
        ((float*)rmu)[L * 68 + cc] = v;   // own slot: no race
    }
    __syncthreads();
    if (t < 64) {
        float s = 0.f, s2 = 0.f;
#pragma unroll
        for (int L = 0; L < NPB; ++L) {
            float v = ((float*)rmu)[L * 68 + t];
            s += v;
            s2 = fmaf(v, v, s2);
        }
        atomicAdd(&stats[t], s);
        atomicAdd(&stats[64 + t], s2);
    }
}

// ---------------------------------------------------------------------------
extern "C" void kernel_launch(void* const* d_in, const int* in_sizes, int n_in,
                              void* d_out, int out_size, void* d_ws, size_t ws_size,
                              hipStream_t stream)
{
    const float* x     = (const float*)d_in[0];
    const int*   eidx  = (const int*)  d_in[1];
    const float* ea    = (const float*)d_in[2];
    const float* w_in  = (const float*)d_in[3];
    const float* b_in  = (const float*)d_in[4];
    const float* w1    = (const float*)d_in[5];
    const float* b1    = (const float*)d_in[6];
    const float* w2    = (const float*)d_in[7];
    const float* b2    = (const float*)d_in[8];
    const float* gamma = (const float*)d_in[9];
    const float* beta  = (const float*)d_in[10];
    const float* w_m1  = (const float*)d_in[11];
    const float* b_m1  = (const float*)d_in[12];
    const float* w_m2  = (const float*)d_in[13];
    const float* b_m2  = (const float*)d_in[14];

    const int M = in_sizes[0] / 64;   // n_nodes
    const int E = in_sizes[1] / 2;    // n_edges
    const int* src = eidx;            // edge_index[0]
    const int* tgt = eidx + E;        // edge_index[1] (aggregation target)

    // ws: hagg f32 | pqh f16 | ends | srcp | part | stats = 29.0 MB
    float* hagg   = (float*)d_ws;
    _Float16* pqh = (_Float16*)(hagg + (size_t)M * 64);
    int* ends     = (int*)(pqh + (size_t)M * 128);
    int* srcp     = ends + M;
    const int nb  = (M + 255) / 256;
    int* part     = srcp + E;
    float* stats  = (float*)(part + nb);
    // d_out scratch: perm[E] | w2h — dead before head writes d_out
    int* perm = (int*)d_out;
    _Float16* w2h = (_Float16*)((char*)d_out + (size_t)E * 4);

    dim3 blk(256);
    const int gm64 = (M + 63) / 64;
    const int gE   = (E + 255) / 256;

    // CSR build + weight pack (+stats zero)
    hipMemsetAsync(ends, 0, (size_t)M * 4, stream);
    hist_tgt<<<gE, blk, 0, stream>>>(tgt, ends, E);
    scan_partial<<<nb, blk, 0, stream>>>(ends, part, M);
    scan_part2<<<1, blk, 0, stream>>>(part, nb);
    scan_add<<<nb, blk, 0, stream>>>(ends, part, M);
    fill_csr<<<gE, blk, 0, stream>>>(tgt, src, ends, perm, srcp, E);
    pack_w2<<<4, blk, 0, stream>>>(w2, w2h, stats);

    // h0 = relu(x @ w_in + b_in)
    gemm_h0<<<gm64, blk, 0, stream>>>(x, w_in, b_in, hagg, M);

    for (int l = 0; l < 2; ++l) {
        const float* w1l = w1 + (size_t)l * 144 * 64;
        if (l == 0)
            gemm_pq<false><<<gm64, blk, 0, stream>>>(hagg, w1l, pqh,
                nullptr, nullptr, nullptr, M);
        else
            gemm_pq<true><<<gm64, blk, 0, stream>>>(hagg, w1l, pqh,
                stats, gamma, beta, M);
        node_agg<<<(M + NPB - 1) / NPB, blk, 0, stream>>>(pqh, ea,
            ends, perm, srcp,
            w1l + 128 * 64, b1 + l * 64, w2h + (size_t)l * 4096, b2 + l * 64,
            hagg, stats + l * 128, M);
    }

    // out = relu(BN1(h) @ w_m1 + b_m1) @ w_m2 + b_m2
    head_fused<<<gm64, blk, 0, stream>>>(hagg, stats + 128, gamma + 64, beta + 64,
        w_m1, b_m1, w_m2, b_m2, (float*)d_out, M);
}